// Round 2
// baseline (160.621 us; speedup 1.0000x reference)
//
#include <hip/hip_runtime.h>
#include <hip/hip_bf16.h>

#define T_TOKENS 8192
#define H_DIM    1024
#define NE       8

typedef __bf16 bf16x8 __attribute__((ext_vector_type(8)));
typedef float  f32x4  __attribute__((ext_vector_type(4)));

__device__ __forceinline__ unsigned short f2bf(float f) {
    union { float f; unsigned u; } v; v.f = f;
    unsigned r = v.u + 0x7FFFu + ((v.u >> 16) & 1u);
    return (unsigned short)(r >> 16);
}

__device__ __forceinline__ void gload_lds16(const unsigned short* g, unsigned short* l) {
    __builtin_amdgcn_global_load_lds(
        (const __attribute__((address_space(1))) unsigned int*)g,
        (__attribute__((address_space(3))) unsigned int*)l, 16, 0, 0);
}

// ---------------- router: logits (f32, exact), top-2, bf16 x ----------------
__global__ __launch_bounds__(256) void moe_router(
    const float* __restrict__ x, const float* __restrict__ gw, const float* __restrict__ gb,
    float* __restrict__ logits, unsigned short* __restrict__ xb,
    int* __restrict__ ridx, float* __restrict__ rp)
{
    __shared__ float gws[H_DIM * 9];   // padded stride 9: conflict-free
    int tid = threadIdx.x;
    for (int i = tid; i < H_DIM; i += 256) {
        const float* s = gw + i * 8;
        float* d = gws + i * 9;
        #pragma unroll
        for (int e = 0; e < 8; ++e) d[e] = s[e];
    }
    __syncthreads();

    int wave = tid >> 6, lane = tid & 63;
    int t = blockIdx.x * 4 + wave;

    float xl[16];
    const float* xrow = x + (size_t)t * H_DIM;
    #pragma unroll
    for (int q = 0; q < 16; ++q) xl[q] = xrow[lane + 64 * q];

    float acc[8] = {0,0,0,0,0,0,0,0};
    #pragma unroll
    for (int q = 0; q < 16; ++q) {
        float xv = xl[q];
        const float* g = &gws[(lane + 64 * q) * 9];
        #pragma unroll
        for (int e = 0; e < 8; ++e) acc[e] += xv * g[e];
    }
    #pragma unroll
    for (int e = 0; e < 8; ++e) {
        float v = acc[e];
        #pragma unroll
        for (int m = 32; m >= 1; m >>= 1) v += __shfl_xor(v, m, 64);
        acc[e] = v + gb[e];
    }
    if (lane == 0) {
        float* lrow = logits + (size_t)t * 8;
        #pragma unroll
        for (int e = 0; e < 8; ++e) lrow[e] = acc[e];
        int b0 = 0; float v0 = acc[0];
        #pragma unroll
        for (int e = 1; e < 8; ++e) if (acc[e] > v0) { v0 = acc[e]; b0 = e; }
        int b1 = -1; float v1 = -1e30f;
        #pragma unroll
        for (int e = 0; e < 8; ++e) if (e != b0 && acc[e] > v1) { v1 = acc[e]; b1 = e; }
        float ex = __expf(v1 - v0);
        float s = 1.0f / (1.0f + ex);
        ridx[2*t] = b0; ridx[2*t+1] = b1;
        rp[2*t] = s;    rp[2*t+1] = ex * s;
    }
    // write bf16 x row
    unsigned short* xbrow = xb + (size_t)t * H_DIM;
    #pragma unroll
    for (int q = 0; q < 16; ++q) xbrow[lane + 64 * q] = f2bf(xl[q]);
}

// ---------------- histogram / scan / scatter ----------------
__global__ void moe_count(const int* __restrict__ ridx, int* __restrict__ cnt) {
    __shared__ int h[8];
    int tid = threadIdx.x;
    if (tid < 8) h[tid] = 0;
    __syncthreads();
    int t = blockIdx.x * 256 + tid;
    atomicAdd(&h[ridx[2*t]], 1);
    atomicAdd(&h[ridx[2*t+1]], 1);
    __syncthreads();
    if (tid < 8 && h[tid]) atomicAdd(&cnt[tid], h[tid]);
}

__global__ void moe_scan(const int* __restrict__ cnt, int* __restrict__ offs,
                         int* __restrict__ running, int* __restrict__ mboffs) {
    if (threadIdx.x == 0) {
        int s = 0, mb = 0;
        for (int e = 0; e < 8; ++e) {
            offs[e] = s; running[e] = s; mboffs[e] = mb;
            s += cnt[e]; mb += (cnt[e] + 127) >> 7;
        }
        offs[8] = s; mboffs[8] = mb;
    }
}

__global__ void moe_scatter(const int* __restrict__ ridx, const float* __restrict__ rp,
                            int* __restrict__ running, int* __restrict__ tlist, float* __restrict__ tp) {
    __shared__ int loc[8];
    __shared__ int base[8];
    int tid = threadIdx.x;
    if (tid < 8) loc[tid] = 0;
    __syncthreads();
    int t = blockIdx.x * 256 + tid;
    int e0 = ridx[2*t], e1 = ridx[2*t+1];
    int l0 = atomicAdd(&loc[e0], 1);
    int l1 = atomicAdd(&loc[e1], 1);
    __syncthreads();
    if (tid < 8 && loc[tid]) base[tid] = atomicAdd(&running[tid], loc[tid]);
    __syncthreads();
    int p0 = base[e0] + l0, p1 = base[e1] + l1;
    tlist[p0] = t; tp[p0] = rp[2*t];
    tlist[p1] = t; tp[p1] = rp[2*t+1];
}

// ---------------- bias pre-combine into out ----------------
__global__ __launch_bounds__(256) void moe_bias(
    const int* __restrict__ ridx, const float* __restrict__ rp,
    const float* __restrict__ eb, float* __restrict__ out)
{
    int idx = blockIdx.x * 256 + threadIdx.x;      // one float4 each, T*H/4 total
    int t = idx >> 8, c = idx & 255;
    int e0 = ridx[2*t], e1 = ridx[2*t+1];
    float p0 = rp[2*t], p1 = rp[2*t+1];
    float4 b0 = ((const float4*)eb)[e0 * 256 + c];
    float4 b1 = ((const float4*)eb)[e1 * 256 + c];
    float4 r;
    r.x = p0*b0.x + p1*b1.x; r.y = p0*b0.y + p1*b1.y;
    r.z = p0*b0.z + p1*b1.z; r.w = p0*b0.w + p1*b1.w;
    ((float4*)out)[idx] = r;
}

// ---------------- W transpose + bf16 convert: Wt[e][n][k] = W[e][k][n] ----------------
__global__ __launch_bounds__(256) void moe_wconv(const float* __restrict__ W, unsigned short* __restrict__ Wt) {
    __shared__ float tile[32][33];
    int e = blockIdx.z;
    int n0 = blockIdx.x * 32, k0 = blockIdx.y * 32;
    int tx = threadIdx.x, ty = threadIdx.y;   // 32 x 8
    const float* src = W + ((size_t)e << 20) + (size_t)k0 * H_DIM + n0;
    #pragma unroll
    for (int i = 0; i < 4; ++i) tile[ty + i*8][tx] = src[(ty + i*8) * H_DIM + tx];
    __syncthreads();
    unsigned short* dst = Wt + ((size_t)e << 20) + (size_t)n0 * H_DIM + k0;
    #pragma unroll
    for (int i = 0; i < 4; ++i) dst[(ty + i*8) * H_DIM + tx] = f2bf(tile[tx][ty + i*8]);
}

// ---------------- grouped expert GEMM: out += p * (x @ W_e) ----------------
// 128x128x64 MFMA, T2 XOR-swizzled LDS (swizzled global source + swizzled ds_read,
// linear global_load_lds dest), 2-phase double-buffered K-loop, compact 1D grid
// with XCD-chunk swizzle.
__global__ __launch_bounds__(256) void moe_gemm(
    const unsigned short* __restrict__ xb, const unsigned short* __restrict__ wt,
    const int* __restrict__ offs, const int* __restrict__ mboffs,
    const int* __restrict__ tlist, const float* __restrict__ tp,
    float* __restrict__ out)
{
    __shared__ __align__(16) unsigned short As[2][128][64];  // [buf][m][k]
    __shared__ __align__(16) unsigned short Bs[2][128][64];  // [buf][n][k]

    int bid = blockIdx.x;
    int w = (bid & 7) * 136 + (bid >> 3);        // XCD-chunk swizzle (1088 % 8 == 0)
    int mb_lin = w >> 3, nb = w & 7;
    if (mb_lin >= mboffs[8]) return;
    int e = 0;
    #pragma unroll
    for (int i = 1; i < 8; ++i) if (mb_lin >= mboffs[i]) e = i;
    int off = offs[e], cnt = offs[e+1] - off;
    int m0 = (mb_lin - mboffs[e]) << 7;
    int n0 = nb << 7;

    int tid = threadIdx.x;
    // Source column pre-swizzle: LDS row written by this thread is r*32+(tid>>3),
    // its linear 16B-slot is (tid&7); fetch global slot (tid&7)^(row&7).
    int scol = ((tid & 7) ^ ((tid >> 3) & 7)) << 3;   // in shorts

    const unsigned short* aptr[4];
    #pragma unroll
    for (int r = 0; r < 4; ++r) {
        int m = m0 + r*32 + (tid >> 3);
        int mc = m < cnt ? m : cnt - 1;
        int t = tlist[off + mc];
        aptr[r] = xb + (size_t)t * H_DIM + scol;
    }
    const unsigned short* wte = wt + ((size_t)e << 20);
    const unsigned short* bptr[4];
    #pragma unroll
    for (int r = 0; r < 4; ++r) {
        int n = n0 + r*32 + (tid >> 3);
        bptr[r] = wte + (size_t)n * H_DIM + scol;
    }

    f32x4 acc[4][4];
    #pragma unroll
    for (int i = 0; i < 4; ++i)
        #pragma unroll
        for (int j = 0; j < 4; ++j) acc[i][j] = (f32x4){0.f,0.f,0.f,0.f};

    int lane = tid & 63, wave = tid >> 6;
    int wm = (wave >> 1) << 6, wn = (wave & 1) << 6;
    int l7 = lane & 7;

    unsigned short* AsF = &As[0][0][0];
    unsigned short* BsF = &Bs[0][0][0];

    // prologue: stage tile 0 into buf 0
    #pragma unroll
    for (int r = 0; r < 4; ++r) gload_lds16(aptr[r], AsF + r*2048 + tid*8);
    #pragma unroll
    for (int r = 0; r < 4; ++r) gload_lds16(bptr[r], BsF + r*2048 + tid*8);
    __syncthreads();

    int cur = 0;
    for (int kk = 0; kk < 16; ++kk) {
        // issue next-tile staging FIRST (hides under MFMA below)
        if (kk < 15) {
            int nxt = cur ^ 1;
            #pragma unroll
            for (int r = 0; r < 4; ++r) gload_lds16(aptr[r] + (kk+1)*64, AsF + nxt*8192 + r*2048 + tid*8);
            #pragma unroll
            for (int r = 0; r < 4; ++r) gload_lds16(bptr[r] + (kk+1)*64, BsF + nxt*8192 + r*2048 + tid*8);
        }
        // compute on buf cur (swizzled ds_read)
        const unsigned short* aRow = AsF + cur*8192 + (wm + (lane & 15)) * 64;
        const unsigned short* bRow = BsF + cur*8192 + (wn + (lane & 15)) * 64;
        #pragma unroll
        for (int k2 = 0; k2 < 2; ++k2) {
            int c0 = (((k2 << 2) + (lane >> 4)) ^ l7) << 3;   // swizzled col (shorts)
            bf16x8 a[4], b[4];
            #pragma unroll
            for (int i = 0; i < 4; ++i) a[i] = *(const bf16x8*)(aRow + i*1024 + c0);
            #pragma unroll
            for (int j = 0; j < 4; ++j) b[j] = *(const bf16x8*)(bRow + j*1024 + c0);
            #pragma unroll
            for (int i = 0; i < 4; ++i)
                #pragma unroll
                for (int j = 0; j < 4; ++j)
                    acc[i][j] = __builtin_amdgcn_mfma_f32_16x16x32_bf16(a[i], b[j], acc[i][j], 0, 0, 0);
        }
        __syncthreads();   // drains this iter's staging; readers of cur done
        cur ^= 1;
    }

    // epilogue: out[t, n] += p * acc
    #pragma unroll
    for (int i = 0; i < 4; ++i) {
        #pragma unroll
        for (int rr = 0; rr < 4; ++rr) {
            int m = m0 + wm + i*16 + ((lane >> 4) << 2) + rr;
            if (m < cnt) {
                int t = tlist[off + m];
                float p = tp[off + m];
                float* orow = out + (size_t)t * H_DIM + n0 + wn + (lane & 15);
                #pragma unroll
                for (int j = 0; j < 4; ++j)
                    unsafeAtomicAdd(orow + j*16, p * acc[i][j][rr]);
            }
        }
    }
}

extern "C" void kernel_launch(void* const* d_in, const int* in_sizes, int n_in,
                              void* d_out, int out_size, void* d_ws, size_t ws_size,
                              hipStream_t stream) {
    const float* x  = (const float*)d_in[0];
    const float* gw = (const float*)d_in[1];
    const float* gb = (const float*)d_in[2];
    const float* ew = (const float*)d_in[3];
    const float* eb = (const float*)d_in[4];

    float* out    = (float*)d_out;
    float* logits = out + (size_t)T_TOKENS * H_DIM;

    char* ws = (char*)d_ws;
    unsigned short* xb   = (unsigned short*)(ws);                       // 16 MiB
    unsigned short* wt   = (unsigned short*)(ws + 16777216);            // 16 MiB
    int*   ridx    = (int*)  (ws + 33554432);                           // 64 KiB
    float* rp      = (float*)(ws + 33619968);                           // 64 KiB
    int*   tlist   = (int*)  (ws + 33685504);                           // 64 KiB
    float* tp      = (float*)(ws + 33751040);                           // 64 KiB
    int*   cnt     = (int*)  (ws + 33816576);                           // 8 ints
    int*   offs    = (int*)  (ws + 33816576 + 64);                      // 9 ints
    int*   running = (int*)  (ws + 33816576 + 128);                     // 8 ints
    int*   mboffs  = (int*)  (ws + 33816576 + 192);                     // 9 ints

    hipMemsetAsync(cnt, 0, 32, stream);

    moe_router <<<T_TOKENS/4, 256, 0, stream>>>(x, gw, gb, logits, xb, ridx, rp);
    moe_wconv  <<<dim3(32, 32, 8), dim3(32, 8), 0, stream>>>(ew, wt);
    moe_count  <<<T_TOKENS/256, 256, 0, stream>>>(ridx, cnt);
    moe_scan   <<<1, 64, 0, stream>>>(cnt, offs, running, mboffs);
    moe_scatter<<<T_TOKENS/256, 256, 0, stream>>>(ridx, rp, running, tlist, tp);
    moe_bias   <<<(T_TOKENS*H_DIM/4)/256, 256, 0, stream>>>(ridx, rp, eb, out);
    moe_gemm   <<<1088, 256, 0, stream>>>(xb, wt, offs, mboffs, tlist, tp, out);
}

// Round 3
// 120.641 us; speedup vs baseline: 1.3314x; 1.3314x over previous
//
#include <hip/hip_runtime.h>
#include <hip/hip_bf16.h>

#define T_TOKENS 8192
#define H_DIM    1024
#define NE       8

typedef __bf16 bf16x8 __attribute__((ext_vector_type(8)));
typedef float  f32x4  __attribute__((ext_vector_type(4)));

__device__ __forceinline__ unsigned short f2bf(float f) {
    union { float f; unsigned u; } v; v.f = f;
    unsigned r = v.u + 0x7FFFu + ((v.u >> 16) & 1u);
    return (unsigned short)(r >> 16);
}
__device__ __forceinline__ float bflo(unsigned w) { union { unsigned u; float f; } v; v.u = w << 16; return v.f; }
__device__ __forceinline__ float bfhi(unsigned w) { union { unsigned u; float f; } v; v.u = w & 0xFFFF0000u; return v.f; }

__device__ __forceinline__ void gload_lds16(const unsigned short* g, unsigned short* l) {
    __builtin_amdgcn_global_load_lds(
        (const __attribute__((address_space(1))) unsigned int*)g,
        (__attribute__((address_space(3))) unsigned int*)l, 16, 0, 0);
}

// ---------------- router: logits (f32, exact), top-2, bf16 x ----------------
__global__ __launch_bounds__(256) void moe_router(
    const float* __restrict__ x, const float* __restrict__ gw, const float* __restrict__ gb,
    float* __restrict__ logits, unsigned short* __restrict__ xb,
    int* __restrict__ ridx, float* __restrict__ rp)
{
    __shared__ float gws[H_DIM * 9];   // padded stride 9: conflict-free
    int tid = threadIdx.x;
    for (int i = tid; i < H_DIM; i += 256) {
        const float* s = gw + i * 8;
        float* d = gws + i * 9;
        #pragma unroll
        for (int e = 0; e < 8; ++e) d[e] = s[e];
    }
    __syncthreads();

    int wave = tid >> 6, lane = tid & 63;
    int t = blockIdx.x * 4 + wave;

    float xl[16];
    const float* xrow = x + (size_t)t * H_DIM;
    #pragma unroll
    for (int q = 0; q < 16; ++q) xl[q] = xrow[lane + 64 * q];

    float acc[8] = {0,0,0,0,0,0,0,0};
    #pragma unroll
    for (int q = 0; q < 16; ++q) {
        float xv = xl[q];
        const float* g = &gws[(lane + 64 * q) * 9];
        #pragma unroll
        for (int e = 0; e < 8; ++e) acc[e] += xv * g[e];
    }
    #pragma unroll
    for (int e = 0; e < 8; ++e) {
        float v = acc[e];
        #pragma unroll
        for (int m = 32; m >= 1; m >>= 1) v += __shfl_xor(v, m, 64);
        acc[e] = v + gb[e];
    }
    if (lane == 0) {
        float* lrow = logits + (size_t)t * 8;
        #pragma unroll
        for (int e = 0; e < 8; ++e) lrow[e] = acc[e];
        int b0 = 0; float v0 = acc[0];
        #pragma unroll
        for (int e = 1; e < 8; ++e) if (acc[e] > v0) { v0 = acc[e]; b0 = e; }
        int b1 = -1; float v1 = -1e30f;
        #pragma unroll
        for (int e = 0; e < 8; ++e) if (e != b0 && acc[e] > v1) { v1 = acc[e]; b1 = e; }
        float ex = __expf(v1 - v0);
        float s = 1.0f / (1.0f + ex);
        ridx[2*t] = b0; ridx[2*t+1] = b1;
        rp[2*t] = s;    rp[2*t+1] = ex * s;
    }
    // write bf16 x row
    unsigned short* xbrow = xb + (size_t)t * H_DIM;
    #pragma unroll
    for (int q = 0; q < 16; ++q) xbrow[lane + 64 * q] = f2bf(xl[q]);
}

// ---------------- histogram / scan / scatter ----------------
__global__ void moe_count(const int* __restrict__ ridx, int* __restrict__ cnt) {
    __shared__ int h[8];
    int tid = threadIdx.x;
    if (tid < 8) h[tid] = 0;
    __syncthreads();
    int t = blockIdx.x * 256 + tid;
    atomicAdd(&h[ridx[2*t]], 1);
    atomicAdd(&h[ridx[2*t+1]], 1);
    __syncthreads();
    if (tid < 8 && h[tid]) atomicAdd(&cnt[tid], h[tid]);
}

__global__ void moe_scan(const int* __restrict__ cnt, int* __restrict__ offs,
                         int* __restrict__ running, int* __restrict__ mboffs) {
    if (threadIdx.x == 0) {
        int s = 0, mb = 0;
        for (int e = 0; e < 8; ++e) {
            offs[e] = s; running[e] = s; mboffs[e] = mb;
            s += cnt[e]; mb += (cnt[e] + 127) >> 7;
        }
        offs[8] = s; mboffs[8] = mb;
    }
}

__global__ void moe_scatter(const int* __restrict__ ridx,
                            int* __restrict__ running, int* __restrict__ tlist, int* __restrict__ ppos) {
    __shared__ int loc[8];
    __shared__ int base[8];
    int tid = threadIdx.x;
    if (tid < 8) loc[tid] = 0;
    __syncthreads();
    int t = blockIdx.x * 256 + tid;
    int e0 = ridx[2*t], e1 = ridx[2*t+1];
    int l0 = atomicAdd(&loc[e0], 1);
    int l1 = atomicAdd(&loc[e1], 1);
    __syncthreads();
    if (tid < 8 && loc[tid]) base[tid] = atomicAdd(&running[tid], loc[tid]);
    __syncthreads();
    int p0 = base[e0] + l0, p1 = base[e1] + l1;
    tlist[p0] = t; ppos[2*t] = p0;
    tlist[p1] = t; ppos[2*t+1] = p1;
}

// ---------------- W transpose + bf16 convert: Wt[e][n][k] = W[e][k][n] ----------------
__global__ __launch_bounds__(256) void moe_wconv(const float* __restrict__ W, unsigned short* __restrict__ Wt) {
    __shared__ float tile[32][33];
    int e = blockIdx.z;
    int n0 = blockIdx.x * 32, k0 = blockIdx.y * 32;
    int tx = threadIdx.x, ty = threadIdx.y;   // 32 x 8
    const float* src = W + ((size_t)e << 20) + (size_t)k0 * H_DIM + n0;
    #pragma unroll
    for (int i = 0; i < 4; ++i) tile[ty + i*8][tx] = src[(ty + i*8) * H_DIM + tx];
    __syncthreads();
    unsigned short* dst = Wt + ((size_t)e << 20) + (size_t)n0 * H_DIM + k0;
    #pragma unroll
    for (int i = 0; i < 4; ++i) dst[(ty + i*8) * H_DIM + tx] = f2bf(tile[tx][ty + i*8]);
}

// ---------------- grouped expert GEMM: eout[slot] = x @ W_e (bf16, plain stores) ----------------
// 128x128x64 MFMA, T2 XOR-swizzled LDS, 2-phase double-buffered K-loop,
// compact 1D grid with XCD-chunk swizzle. No atomics: each (slot, n) written once.
__global__ __launch_bounds__(256) void moe_gemm(
    const unsigned short* __restrict__ xb, const unsigned short* __restrict__ wt,
    const int* __restrict__ offs, const int* __restrict__ mboffs,
    const int* __restrict__ tlist, unsigned short* __restrict__ eout)
{
    __shared__ __align__(16) unsigned short As[2][128][64];  // [buf][m][k]
    __shared__ __align__(16) unsigned short Bs[2][128][64];  // [buf][n][k]

    int bid = blockIdx.x;
    int w = (bid & 7) * 136 + (bid >> 3);        // XCD-chunk swizzle (1088 % 8 == 0)
    int mb_lin = w >> 3, nb = w & 7;
    if (mb_lin >= mboffs[8]) return;
    int e = 0;
    #pragma unroll
    for (int i = 1; i < 8; ++i) if (mb_lin >= mboffs[i]) e = i;
    int off = offs[e], cnt = offs[e+1] - off;
    int m0 = (mb_lin - mboffs[e]) << 7;
    int n0 = nb << 7;

    int tid = threadIdx.x;
    // Source column pre-swizzle: LDS row written by this thread is r*32+(tid>>3),
    // its linear 16B-slot is (tid&7); fetch global slot (tid&7)^(row&7).
    int scol = ((tid & 7) ^ ((tid >> 3) & 7)) << 3;   // in shorts

    const unsigned short* aptr[4];
    #pragma unroll
    for (int r = 0; r < 4; ++r) {
        int m = m0 + r*32 + (tid >> 3);
        int mc = m < cnt ? m : cnt - 1;
        int t = tlist[off + mc];
        aptr[r] = xb + (size_t)t * H_DIM + scol;
    }
    const unsigned short* wte = wt + ((size_t)e << 20);
    const unsigned short* bptr[4];
    #pragma unroll
    for (int r = 0; r < 4; ++r) {
        int n = n0 + r*32 + (tid >> 3);
        bptr[r] = wte + (size_t)n * H_DIM + scol;
    }

    f32x4 acc[4][4];
    #pragma unroll
    for (int i = 0; i < 4; ++i)
        #pragma unroll
        for (int j = 0; j < 4; ++j) acc[i][j] = (f32x4){0.f,0.f,0.f,0.f};

    int lane = tid & 63, wave = tid >> 6;
    int wm = (wave >> 1) << 6, wn = (wave & 1) << 6;
    int l7 = lane & 7;

    unsigned short* AsF = &As[0][0][0];
    unsigned short* BsF = &Bs[0][0][0];

    // prologue: stage tile 0 into buf 0
    #pragma unroll
    for (int r = 0; r < 4; ++r) gload_lds16(aptr[r], AsF + r*2048 + tid*8);
    #pragma unroll
    for (int r = 0; r < 4; ++r) gload_lds16(bptr[r], BsF + r*2048 + tid*8);
    __syncthreads();

    int cur = 0;
    for (int kk = 0; kk < 16; ++kk) {
        // issue next-tile staging FIRST (hides under MFMA below)
        if (kk < 15) {
            int nxt = cur ^ 1;
            #pragma unroll
            for (int r = 0; r < 4; ++r) gload_lds16(aptr[r] + (kk+1)*64, AsF + nxt*8192 + r*2048 + tid*8);
            #pragma unroll
            for (int r = 0; r < 4; ++r) gload_lds16(bptr[r] + (kk+1)*64, BsF + nxt*8192 + r*2048 + tid*8);
        }
        // compute on buf cur (swizzled ds_read)
        const unsigned short* aRow = AsF + cur*8192 + (wm + (lane & 15)) * 64;
        const unsigned short* bRow = BsF + cur*8192 + (wn + (lane & 15)) * 64;
        #pragma unroll
        for (int k2 = 0; k2 < 2; ++k2) {
            int c0 = (((k2 << 2) + (lane >> 4)) ^ l7) << 3;   // swizzled col (shorts)
            bf16x8 a[4], b[4];
            #pragma unroll
            for (int i = 0; i < 4; ++i) a[i] = *(const bf16x8*)(aRow + i*1024 + c0);
            #pragma unroll
            for (int j = 0; j < 4; ++j) b[j] = *(const bf16x8*)(bRow + j*1024 + c0);
            #pragma unroll
            for (int i = 0; i < 4; ++i)
                #pragma unroll
                for (int j = 0; j < 4; ++j)
                    acc[i][j] = __builtin_amdgcn_mfma_f32_16x16x32_bf16(a[i], b[j], acc[i][j], 0, 0, 0);
        }
        __syncthreads();   // drains this iter's staging; readers of cur done
        cur ^= 1;
    }

    // epilogue: eout[off+m, n] = bf16(acc)  (plain stores, each element written once)
    #pragma unroll
    for (int i = 0; i < 4; ++i) {
        #pragma unroll
        for (int rr = 0; rr < 4; ++rr) {
            int m = m0 + wm + i*16 + ((lane >> 4) << 2) + rr;
            if (m < cnt) {
                unsigned short* erow = eout + (size_t)(off + m) * H_DIM + n0 + wn + (lane & 15);
                #pragma unroll
                for (int j = 0; j < 4; ++j)
                    erow[j*16] = f2bf(acc[i][j][rr]);
            }
        }
    }
}

// ---------------- combine: out[t] = p0*(v0 + b_e0) + p1*(v1 + b_e1) ----------------
__global__ __launch_bounds__(256) void moe_combine(
    const int* __restrict__ ridx, const float* __restrict__ rp, const int* __restrict__ ppos,
    const unsigned short* __restrict__ eout, const float* __restrict__ eb, float* __restrict__ out)
{
    int idx = blockIdx.x * 256 + threadIdx.x;   // T * H/8 threads
    int t = idx >> 7, c = (idx & 127) << 3;
    int e0 = ridx[2*t], e1 = ridx[2*t+1];
    float p0 = rp[2*t],  p1 = rp[2*t+1];
    const unsigned* u0 = (const unsigned*)(eout + (size_t)ppos[2*t]   * H_DIM + c);
    const unsigned* u1 = (const unsigned*)(eout + (size_t)ppos[2*t+1] * H_DIM + c);
    uint4 v0 = *(const uint4*)u0;
    uint4 v1 = *(const uint4*)u1;
    const float* b0 = eb + e0 * H_DIM + c;
    const float* b1 = eb + e1 * H_DIM + c;
    float r[8];
    const unsigned* w0 = &v0.x;
    const unsigned* w1 = &v1.x;
    #pragma unroll
    for (int k = 0; k < 4; ++k) {
        r[2*k]   = p0 * (bflo(w0[k]) + b0[2*k])   + p1 * (bflo(w1[k]) + b1[2*k]);
        r[2*k+1] = p0 * (bfhi(w0[k]) + b0[2*k+1]) + p1 * (bfhi(w1[k]) + b1[2*k+1]);
    }
    float4* op = (float4*)(out + (size_t)t * H_DIM + c);
    op[0] = make_float4(r[0], r[1], r[2], r[3]);
    op[1] = make_float4(r[4], r[5], r[6], r[7]);
}

extern "C" void kernel_launch(void* const* d_in, const int* in_sizes, int n_in,
                              void* d_out, int out_size, void* d_ws, size_t ws_size,
                              hipStream_t stream) {
    const float* x  = (const float*)d_in[0];
    const float* gw = (const float*)d_in[1];
    const float* gb = (const float*)d_in[2];
    const float* ew = (const float*)d_in[3];
    const float* eb = (const float*)d_in[4];

    float* out    = (float*)d_out;
    float* logits = out + (size_t)T_TOKENS * H_DIM;

    char* ws = (char*)d_ws;
    unsigned short* xb   = (unsigned short*)(ws);                       // 16 MiB
    unsigned short* wt   = (unsigned short*)(ws + 16777216);            // 16 MiB
    unsigned short* eout = (unsigned short*)(ws + 33554432);            // 32 MiB (16384 x 1024 bf16)
    int*   ridx    = (int*)  (ws + 67108864);                           // 64 KiB
    float* rp      = (float*)(ws + 67174400);                           // 64 KiB
    int*   tlist   = (int*)  (ws + 67239936);                           // 64 KiB
    int*   ppos    = (int*)  (ws + 67305472);                           // 64 KiB
    int*   cnt     = (int*)  (ws + 67371008);                           // 8 ints
    int*   offs    = (int*)  (ws + 67371008 + 64);                      // 9 ints
    int*   running = (int*)  (ws + 67371008 + 128);                     // 8 ints
    int*   mboffs  = (int*)  (ws + 67371008 + 192);                     // 9 ints

    hipMemsetAsync(cnt, 0, 32, stream);

    moe_router <<<T_TOKENS/4, 256, 0, stream>>>(x, gw, gb, logits, xb, ridx, rp);
    moe_wconv  <<<dim3(32, 32, 8), dim3(32, 8), 0, stream>>>(ew, wt);
    moe_count  <<<T_TOKENS/256, 256, 0, stream>>>(ridx, cnt);
    moe_scan   <<<1, 64, 0, stream>>>(cnt, offs, running, mboffs);
    moe_scatter<<<T_TOKENS/256, 256, 0, stream>>>(ridx, running, tlist, ppos);
    moe_gemm   <<<1088, 256, 0, stream>>>(xb, wt, offs, mboffs, tlist, eout);
    moe_combine<<<(T_TOKENS*H_DIM/8)/256, 256, 0, stream>>>(ridx, rp, ppos, eout, eb, out);
}